// Round 16
// baseline (134.585 us; speedup 1.0000x reference)
//
#include <hip/hip_runtime.h>
#include <hip/hip_bf16.h>
#include <math.h>

typedef __bf16 bf16;
typedef __bf16 bf16x4 __attribute__((ext_vector_type(4)));
typedef __bf16 bf16x8 __attribute__((ext_vector_type(8)));
typedef float  f32x4  __attribute__((ext_vector_type(4)));

#define MM 2048   // seq len
#define DD 1024   // model dim
#define HD 64    // head dim

// async global->LDS, 16B per lane. LDS dest must be wave-uniform base + lane*16.
__device__ __forceinline__ void gload16(const void* g, void* l) {
  __builtin_amdgcn_global_load_lds((const __attribute__((address_space(1))) void*)g,
                                   (__attribute__((address_space(3))) void*)l, 16, 0, 0);
}

// ---------------- fp32 -> bf16 conversion (all tensors, one launch) -------
__global__ __launch_bounds__(256) void k_cvt_all(
    const float* __restrict__ x,   const float* __restrict__ wq,
    const float* __restrict__ wk,  const float* __restrict__ wv,
    const float* __restrict__ ipw, const float* __restrict__ ow,
    bf16* __restrict__ xb,  bf16* __restrict__ wqb, bf16* __restrict__ wkb,
    bf16* __restrict__ wvb, bf16* __restrict__ ipwb, bf16* __restrict__ owb)
{
  int bid = blockIdx.x;
  const float* s; bf16* d; int base;
  if (bid < 4096)       { s = x;   d = xb;   base = bid; }
  else if (bid < 5120)  { s = wq;  d = wqb;  base = bid - 4096; }
  else if (bid < 6144)  { s = wk;  d = wkb;  base = bid - 5120; }
  else if (bid < 7168)  { s = wv;  d = wvb;  base = bid - 6144; }
  else if (bid < 10240) { s = ipw; d = ipwb; base = bid - 7168; }
  else                  { s = ow;  d = owb;  base = bid - 10240; }
  int i = base*256 + threadIdx.x;          // float4 index
  float4 v = ((const float4*)s)[i];
  bf16x4 o;
  o[0]=(bf16)v.x; o[1]=(bf16)v.y; o[2]=(bf16)v.z; o[3]=(bf16)v.w;
  ((bf16x4*)d)[i] = o;
}

// ---------------- shared GEMM core (8-wave): C(128x128) = A * B^T ---------
// 512 threads = 8 waves (4 row x 2 col), wave does 32x64 out (2x4 frags).
// BK=64: 2 LDS buffers x (A 16KB + B 16KB) = 64KB -> 2 blocks/CU,
// 16 waves/CU = 4 waves/SIMD. Per K-tile: barrier; issue 4 gload16 for
// kt+1; vmcnt(4) counted; barrier; 12 ds_read_b128; 16 MFMA/wave.
// 8-chunk rotation layout -> 0 conflicts (r4-verified structure).
__device__ __forceinline__ void gemm_core8(const bf16* __restrict__ A,
                                           const bf16* __restrict__ Bw,
                                           const int row0, const int col0,
                                           bf16* __restrict__ sA, bf16* __restrict__ sB,
                                           f32x4 (&acc)[2][4])
{
  const int t = threadIdx.x;                 // 0..511
  #pragma unroll
  for (int m=0;m<2;m++)
    #pragma unroll
    for (int n=0;n<4;n++)
      acc[m][n] = (f32x4){0.f,0.f,0.f,0.f};

  const int srow = t >> 3;
  const int lch  = ((t & 7) - (srow & 7)) & 7;
  const bf16* gA = A  + (size_t)(row0 + srow)*DD + lch*8;
  const bf16* gB = Bw + (size_t)(col0 + srow)*DD + lch*8;
  char* lA = (char*)sA + t*16;               // 8KB per issue-half
  char* lB = (char*)sB + t*16;

  const int lane = t & 63, wid = t >> 6;
  const int wr = wid >> 1, wc = wid & 1;     // 4 x 2 wave grid
  const int fr = lane & 15, fg = lane >> 4;
  const int fr7 = fr & 7;

  // prologue: stage tile 0 into buffer 0
  gload16(gA,                 lA);
  gload16(gA + (size_t)64*DD, lA + 8192);
  gload16(gB,                 lB);
  gload16(gB + (size_t)64*DD, lB + 8192);

  for (int kt = 0; kt < 16; ++kt) {
    const int buf = kt & 1;
    __builtin_amdgcn_s_barrier();        // all waves done reading buf^1
    if (kt < 15) {
      const int nb = buf ^ 1;
      const int ko = (kt + 1) * 64;
      gload16(gA + ko,                 lA + nb*16384);
      gload16(gA + (size_t)64*DD + ko, lA + nb*16384 + 8192);
      gload16(gB + ko,                 lB + nb*16384);
      gload16(gB + (size_t)64*DD + ko, lB + nb*16384 + 8192);
      asm volatile("s_waitcnt vmcnt(4)" ::: "memory");   // kt's 4 done
    } else {
      asm volatile("s_waitcnt vmcnt(0)" ::: "memory");
    }
    __builtin_amdgcn_s_barrier();        // all waves' kt DMA drained
    const char* bA = (const char*)sA + buf*16384;
    const char* bB = (const char*)sB + buf*16384;
    bf16x8 aF[2][2], bF[2][4];
    #pragma unroll
    for (int kb=0;kb<2;kb++) {
      #pragma unroll
      for (int m=0;m<2;m++)
        aF[kb][m] = *(const bf16x8*)(bA + (wr*32 + m*16 + fr)*128 + ((kb*4 + fg + fr7)&7)*16);
      #pragma unroll
      for (int n=0;n<4;n++)
        bF[kb][n] = *(const bf16x8*)(bB + (wc*64 + n*16 + fr)*128 + ((kb*4 + fg + fr7)&7)*16);
    }
    __builtin_amdgcn_s_setprio(1);
    #pragma unroll
    for (int kb=0;kb<2;kb++)
      #pragma unroll
      for (int m=0;m<2;m++)
        #pragma unroll
        for (int n=0;n<4;n++)
          acc[m][n] = __builtin_amdgcn_mfma_f32_16x16x32_bf16(aF[kb][m], bF[kb][n], acc[m][n], 0, 0, 0);
    __builtin_amdgcn_s_setprio(0);
  }
}

// ---------------- GEMM 1: q/k/v = rope(x @ W^T), z picks W ----------------
__global__ __launch_bounds__(512, 2) void k_gemm_rope(
    const bf16* __restrict__ X, const bf16* __restrict__ Wq,
    const bf16* __restrict__ Wk, const bf16* __restrict__ Wv,
    bf16* __restrict__ QKV)
{
  __shared__ bf16 sA[2*128*64];   // 32 KB
  __shared__ bf16 sB[2*128*64];   // 32 KB
  const int row0 = blockIdx.x * 128;
  const int col0 = blockIdx.y * 128;
  const int z = blockIdx.z;
  const bf16* Bw = (z==0) ? Wq : ((z==1) ? Wk : Wv);
  f32x4 acc[2][4];
  gemm_core8(X, Bw, row0, col0, sA, sB, acc);

  bf16* outp = QKV + (size_t)z * (4096u*1024u);
  const int lane = threadIdx.x & 63, wid = threadIdx.x >> 6;
  const int wr = wid >> 1, wc = wid & 1;
  const int fr = lane & 15, fg = lane >> 4;
  #pragma unroll
  for (int n=0;n<4;n++) {
    const int gc = col0 + wc*64 + n*16 + fr;
    const int i2 = gc >> 1;
    // theta = 10000^(-2*(i-1)/1024) = exp((i-1) * (-2*ln(1e4)/1024))
    const float theta = __expf(((float)i2 - 1.0f) * (-2.0f * 9.210340371976184f / 1024.0f));
    #pragma unroll
    for (int m=0;m<2;m++) {
      #pragma unroll
      for (int r=0;r<4;r++) {
        const int gr = row0 + wr*32 + m*16 + fg*4 + r;
        const float v  = acc[m][n][r];
        const float pv = __shfl_xor(v, 1);      // partner column of the pair
        const int pos = gr & (MM-1);
        float sv, cv;
        __sincosf((float)pos * theta, &sv, &cv);
        const float res = (gc & 1) ? (v*cv - pv*sv) : (v*cv + pv*sv);
        outp[(size_t)gr * DD + gc] = (bf16)res;
      }
    }
  }
}

// ------- GEMM 2: qh/kh = q/k @ Wi^T + b (bf16), vh stored TRANSPOSED ------
// QH pre-scaled by 0.125*log2(e): attention scores land in log2 units.
__global__ __launch_bounds__(512, 2) void k_gemm_proj(
    const bf16* __restrict__ QKV, const bf16* __restrict__ IPW,
    const float* __restrict__ IPB,
    bf16* __restrict__ QH, bf16* __restrict__ KH, bf16* __restrict__ VT)
{
  __shared__ bf16 sA[2*128*64];
  __shared__ bf16 sB[2*128*64];
  const int row0 = blockIdx.x * 128;
  const int col0 = blockIdx.y * 128;
  const int z = blockIdx.z;
  const bf16* A  = QKV + (size_t)z * (4096u*1024u);
  const bf16* Bw = IPW + (size_t)z * (1024u*1024u);
  const float* bias = IPB + z * DD;
  f32x4 acc[2][4];
  gemm_core8(A, Bw, row0, col0, sA, sB, acc);

  const int lane = threadIdx.x & 63, wid = threadIdx.x >> 6;
  const int wr = wid >> 1, wc = wid & 1;
  const int fr = lane & 15, fg = lane >> 4;
  if (z < 2) {
    bf16* outp = (z==0) ? QH : KH;
    const float vscale = (z==0) ? 0.18033688011112042f : 1.0f;  // 0.125*log2e
    #pragma unroll
    for (int n=0;n<4;n++) {
      const int gc = col0 + wc*64 + n*16 + fr;
      const float bs = bias[gc];
      #pragma unroll
      for (int m=0;m<2;m++) {
        #pragma unroll
        for (int r=0;r<4;r++) {
          const int gr = row0 + wr*32 + m*16 + fg*4 + r;
          outp[(size_t)gr * DD + gc] = (bf16)((acc[m][n][r] + bs) * vscale);
        }
      }
    }
  } else {
    // VT layout: (B, D, M) so attention PV B-frags read contiguous along m
    #pragma unroll
    for (int n=0;n<4;n++) {
      const int gc = col0 + wc*64 + n*16 + fr;
      const float bs = bias[gc];
      #pragma unroll
      for (int m=0;m<2;m++) {
        const int gr0 = row0 + wr*32 + m*16 + fg*4;   // 4 consecutive rows
        const int b  = gr0 >> 11;
        const int m0 = gr0 & (MM-1);
        bf16x4 pk;
        #pragma unroll
        for (int r=0;r<4;r++) pk[r] = (bf16)(acc[m][n][r] + bs);
        *(bf16x4*)(VT + ((size_t)b*DD + gc)*MM + m0) = pk;
      }
    }
  }
}

// ---------------- flash attention (causal), KVBLK=64 ----------------------
// r15 base (measured 48us) + PV-LAG PIPELINE (T15 single-state):
// at iter kt, PV(kt-1) runs FIRST from registers (aP0/aP1 + vreg[8] read one
// iteration earlier), then V(kt) frags -> vreg, then QK(kt), then softmax(kt)
// -> new aP. PV's MFMAs fill the matrix pipe while softmax's exp2 chain runs
// on VALU, and the P LDS-roundtrip is no longer serially appended to PV.
// Single V/P register state: PV consumes before readV/softmax overwrite
// (plain in-order code; vreg indexed only by static unroll indices).
// Everything else identical to r15: 1024 blocks LPT, XCD-grouped, 40KB LDS,
// 2-buffer K/V, fixed-max log2 softmax, MFMA row-sum, zero-shuffle epilogue.
__global__ __launch_bounds__(256) void k_attn(
    const bf16* __restrict__ QH, const bf16* __restrict__ KH,
    const bf16* __restrict__ VT, bf16* __restrict__ O)
{
  __shared__ bf16 sK[2*64*64];    // [buf][kv][d] rows of 128B, swizzled
  __shared__ bf16 sV[2*64*64];    // [buf][d][kv] (from VT), swizzled
  __shared__ bf16 sP[4*16*64];    // per-wave P tile [16 q][64 kv] swizzled
  const int idx = blockIdx.x;
  const int xcd = idx & 7;
  const int rr  = idx >> 3;                  // 0..127
  const int combo = xcd*4 + (rr & 3);        // 0..31 (4 combos per XCD)
  const int b = combo >> 4, h = combo & 15;
  const int qt = 31 - (rr >> 2);             // LPT: longest q-tiles first
  const int t = threadIdx.x, lane = t & 63, wid = t >> 6;
  const int fr = lane & 15, fg = lane >> 4;
  const int swzP = (fr & 7) << 4;
  const int q0 = qt * 64;
  const int qg = q0 + wid*16 + fr;           // this lane's q row

  // staging geometry (pre-swizzled global source, linear LDS dest t*16)
  const int srow = t >> 3;                       // 0..31
  const int cc   = (t & 7) ^ (srow & 7);
  const bf16* gK0 = KH + ((size_t)b*MM + srow)*DD + h*HD + cc*8;
  const bf16* gK1 = gK0 + (size_t)32*DD;
  const bf16* gV0 = VT + ((size_t)b*DD + h*HD + srow)*MM + cc*8;
  const bf16* gV1 = gV0 + (size_t)32*MM;
  char* lK = (char*)sK + t*16;
  char* lV = (char*)sV + t*16;
  char* sPw = (char*)(sP + wid*16*64);

  const bf16* qp = QH + ((size_t)b*MM + qg)*DD + h*HD + fg*8;
  bf16x8 aQ0 = *(const bf16x8*)qp;
  bf16x8 aQ1 = *(const bf16x8*)(qp + 32);

  bf16x8 ones;
  #pragma unroll
  for (int j=0;j<8;j++) ones[j] = (bf16)1.0f;

  // stage tile 0 into buffer 0
  gload16(gK0, lK);  gload16(gK1, lK + 4096);
  gload16(gV0, lV);  gload16(gV1, lV + 4096);

  f32x4 o_acc[4];
  #pragma unroll
  for (int n=0;n<4;n++) o_acc[n] = (f32x4){0.f,0.f,0.f,0.f};
  f32x4 lacc = (f32x4){0.f,0.f,0.f,0.f};     // softmax denominator via MFMA
  const f32x4 minit = (f32x4){-32.f,-32.f,-32.f,-32.f};

  // pipeline registers: V(kt) fragments + P(kt) A-operands, single state
  bf16x8 vreg[8];
  bf16x8 aP0, aP1;

  for (int kt = 0; kt <= qt; ++kt) {
    const int buf = kt & 1;
    asm volatile("s_waitcnt vmcnt(0)" ::: "memory");  // own tile-kt DMA done
    __builtin_amdgcn_s_barrier();          // all waves' DMA done; buf^1 free
    if (kt < qt) {                         // stage next tile into buf^1
      const int nb = buf ^ 1;
      gload16(gK0 + (size_t)(kt+1)*64*DD, lK + nb*8192);
      gload16(gK1 + (size_t)(kt+1)*64*DD, lK + nb*8192 + 4096);
      gload16(gV0 + (kt+1)*64,            lV + nb*8192);
      gload16(gV1 + (kt+1)*64,            lV + nb*8192 + 4096);
    }
    const char* bKb = (const char*)sK + buf*8192;
    const char* bVb = (const char*)sV + buf*8192;

    // PV(kt-1): o_acc += P(kt-1) V(kt-1), l += P @ ones  (all from regs)
    if (kt > 0) {
      __builtin_amdgcn_s_setprio(1);
      #pragma unroll
      for (int n=0;n<4;n++) {
        o_acc[n] = __builtin_amdgcn_mfma_f32_16x16x32_bf16(aP0, vreg[2*n],   o_acc[n], 0, 0, 0);
        o_acc[n] = __builtin_amdgcn_mfma_f32_16x16x32_bf16(aP1, vreg[2*n+1], o_acc[n], 0, 0, 0);
      }
      lacc = __builtin_amdgcn_mfma_f32_16x16x32_bf16(aP0, ones, lacc, 0, 0, 0);
      lacc = __builtin_amdgcn_mfma_f32_16x16x32_bf16(aP1, ones, lacc, 0, 0, 0);
      __builtin_amdgcn_s_setprio(0);
    }

    // read V(kt) fragments into regs (used next iteration / final PV)
    #pragma unroll
    for (int n=0;n<4;n++) {
      const int rowV = n*16 + fr;
      vreg[2*n]   = *(const bf16x8*)(bVb + rowV*128 + ((fg*16) ^ ((rowV&7)<<4)));
      vreg[2*n+1] = *(const bf16x8*)(bVb + rowV*128 + ((64 + fg*16) ^ ((rowV&7)<<4)));
    }

    // S^T - 32 = K Q^T + (-32) : lane holds S[kv=n*16+fg*4+r][q=fr] - 32
    f32x4 sacc[4];
    #pragma unroll
    for (int n=0;n<4;n++) sacc[n] = minit;
    __builtin_amdgcn_s_setprio(1);
    #pragma unroll
    for (int kb=0;kb<2;kb++) {
      const bf16x8 q = kb ? aQ1 : aQ0;
      #pragma unroll
      for (int n=0;n<4;n++) {
        const int rowA = n*16 + fr;
        bf16x8 aK = *(const bf16x8*)(bKb + rowA*128 + ((kb*64 + fg*16) ^ ((rowA&7)<<4)));
        sacc[n] = __builtin_amdgcn_mfma_f32_16x16x32_bf16(aK, q, sacc[n], 0, 0, 0);
      }
    }
    __builtin_amdgcn_s_setprio(0);

    // P = 2^(s - 32), masked entries -> 0  (no running max, no subtract)
    const bool diag = (kt == qt);
    float ps[16];
    #pragma unroll
    for (int n=0;n<4;n++)
      #pragma unroll
      for (int r=0;r<4;r++) {
        float xx = sacc[n][r];
        if (diag) {
          const int kvg = kt*64 + n*16 + fg*4 + r;
          if (kvg > qg) xx = -INFINITY;
        }
        ps[n*4+r] = exp2f(xx);
      }
    #pragma unroll
    for (int n=0;n<4;n++) {
      bf16x4 pk;
      #pragma unroll
      for (int r=0;r<4;r++) pk[r] = (bf16)ps[n*4+r];
      *(bf16x4*)(sPw + fr*128 + ((n*32 + fg*8) ^ swzP)) = pk;
    }
    asm volatile("s_waitcnt lgkmcnt(0)" ::: "memory");  // P visible wave-wide

    aP0 = *(const bf16x8*)(sPw + fr*128 + ((fg*16) ^ swzP));
    aP1 = *(const bf16x8*)(sPw + fr*128 + ((64 + fg*16) ^ swzP));
    __builtin_amdgcn_s_barrier();          // all waves done with buf kt
  }

  // final PV (tile qt) from regs
  __builtin_amdgcn_s_setprio(1);
  #pragma unroll
  for (int n=0;n<4;n++) {
    o_acc[n] = __builtin_amdgcn_mfma_f32_16x16x32_bf16(aP0, vreg[2*n],   o_acc[n], 0, 0, 0);
    o_acc[n] = __builtin_amdgcn_mfma_f32_16x16x32_bf16(aP1, vreg[2*n+1], o_acc[n], 0, 0, 0);
  }
  lacc = __builtin_amdgcn_mfma_f32_16x16x32_bf16(aP0, ones, lacc, 0, 0, 0);
  lacc = __builtin_amdgcn_mfma_f32_16x16x32_bf16(aP1, ones, lacc, 0, 0, 0);
  __builtin_amdgcn_s_setprio(0);

  // epilogue: l[q=fg*4+r] sits in lacc[r] of every lane -> no shuffles
  #pragma unroll
  for (int r=0;r<4;r++) {
    const int qq = q0 + wid*16 + fg*4 + r;
    const float inv = 1.0f / lacc[r];
    #pragma unroll
    for (int n=0;n<4;n++) {
      O[((size_t)b*MM + qq)*DD + h*HD + n*16 + fr] = (bf16)(o_acc[n][r] * inv);
    }
  }
}

// ---------------- GEMM 3: out = O @ out_w^T + out_b (fp32 out) ------------
__global__ __launch_bounds__(512, 2) void k_gemm_out(
    const bf16* __restrict__ A, const bf16* __restrict__ OW,
    const float* __restrict__ OBIAS, float* __restrict__ outp)
{
  __shared__ bf16 sA[2*128*64];
  __shared__ bf16 sB[2*128*64];
  const int row0 = blockIdx.x * 128;
  const int col0 = blockIdx.y * 128;
  f32x4 acc[2][4];
  gemm_core8(A, OW, row0, col0, sA, sB, acc);
  const int lane = threadIdx.x & 63, wid = threadIdx.x >> 6;
  const int wr = wid >> 1, wc = wid & 1;
  const int fr = lane & 15, fg = lane >> 4;
  #pragma unroll
  for (int n=0;n<4;n++) {
    const int gc = col0 + wc*64 + n*16 + fr;
    const float bs = OBIAS[gc];
    #pragma unroll
    for (int m=0;m<2;m++) {
      #pragma unroll
      for (int r=0;r<4;r++) {
        const int gr = row0 + wr*32 + m*16 + fg*4 + r;
        outp[(size_t)gr * DD + gc] = acc[m][n][r] + bs;
      }
    }
  }
}

// ---------------- host launcher -------------------------------------------
extern "C" void kernel_launch(void* const* d_in, const int* in_sizes, int n_in,
                              void* d_out, int out_size, void* d_ws, size_t ws_size,
                              hipStream_t stream)
{
  (void)in_sizes; (void)n_in; (void)out_size; (void)ws_size;
  const float* x   = (const float*)d_in[0];
  const float* wq  = (const float*)d_in[1];
  const float* wk  = (const float*)d_in[2];
  const float* wv  = (const float*)d_in[3];
  const float* ipw = (const float*)d_in[4];
  const float* ipb = (const float*)d_in[5];
  const float* ow  = (const float*)d_in[6];
  const float* ob  = (const float*)d_in[7];
  float* outp = (float*)d_out;

  char* ws = (char*)d_ws;
  const size_t MB = 1u << 20;
  bf16* xb   = (bf16*)(ws + 0*MB);    // 8 MB  (4096x1024)
  bf16* wqb  = (bf16*)(ws + 8*MB);    // 2 MB
  bf16* wkb  = (bf16*)(ws + 10*MB);   // 2 MB
  bf16* wvb  = (bf16*)(ws + 12*MB);   // 2 MB
  bf16* ipwb = (bf16*)(ws + 14*MB);   // 6 MB  (3072x1024)
  bf16* owb  = (bf16*)(ws + 20*MB);   // 2 MB
  bf16* QKV  = (bf16*)(ws + 22*MB);   // 24 MB (3 x 4096x1024)
  bf16* QH   = (bf16*)(ws + 46*MB);   // 8 MB  (pre-scaled by 0.125*log2e)
  bf16* KH   = (bf16*)(ws + 54*MB);   // 8 MB
  bf16* VT   = (bf16*)(ws + 62*MB);   // 8 MB  (2 x 1024 x 2048, transposed)
  bf16* Ob   = (bf16*)(ws + 70*MB);   // 8 MB

  k_cvt_all<<<11264, 256, 0, stream>>>(x, wq, wk, wv, ipw, ow,
                                       xb, wqb, wkb, wvb, ipwb, owb);
  k_gemm_rope<<<dim3(32,8,3), 512, 0, stream>>>(xb, wqb, wkb, wvb, QKV);
  k_gemm_proj<<<dim3(32,8,3), 512, 0, stream>>>(QKV, ipwb, ipb, QH, KH, VT);
  k_attn<<<1024, 256, 0, stream>>>(QH, KH, VT, Ob);
  k_gemm_out<<<dim3(32,8,1), 512, 0, stream>>>(Ob, owb, ob, outp);
}

// Round 17
// 128.625 us; speedup vs baseline: 1.0463x; 1.0463x over previous
//
#include <hip/hip_runtime.h>
#include <hip/hip_bf16.h>
#include <math.h>

typedef __bf16 bf16;
typedef __bf16 bf16x4 __attribute__((ext_vector_type(4)));
typedef __bf16 bf16x8 __attribute__((ext_vector_type(8)));
typedef float  f32x4  __attribute__((ext_vector_type(4)));

#define MM 2048   // seq len
#define DD 1024   // model dim
#define HD 64    // head dim

// async global->LDS, 16B per lane. LDS dest must be wave-uniform base + lane*16.
__device__ __forceinline__ void gload16(const void* g, void* l) {
  __builtin_amdgcn_global_load_lds((const __attribute__((address_space(1))) void*)g,
                                   (__attribute__((address_space(3))) void*)l, 16, 0, 0);
}

// ---------------- fp32 -> bf16 conversion (all tensors, one launch) -------
__global__ __launch_bounds__(256) void k_cvt_all(
    const float* __restrict__ x,   const float* __restrict__ wq,
    const float* __restrict__ wk,  const float* __restrict__ wv,
    const float* __restrict__ ipw, const float* __restrict__ ow,
    bf16* __restrict__ xb,  bf16* __restrict__ wqb, bf16* __restrict__ wkb,
    bf16* __restrict__ wvb, bf16* __restrict__ ipwb, bf16* __restrict__ owb)
{
  int bid = blockIdx.x;
  const float* s; bf16* d; int base;
  if (bid < 4096)       { s = x;   d = xb;   base = bid; }
  else if (bid < 5120)  { s = wq;  d = wqb;  base = bid - 4096; }
  else if (bid < 6144)  { s = wk;  d = wkb;  base = bid - 5120; }
  else if (bid < 7168)  { s = wv;  d = wvb;  base = bid - 6144; }
  else if (bid < 10240) { s = ipw; d = ipwb; base = bid - 7168; }
  else                  { s = ow;  d = owb;  base = bid - 10240; }
  int i = base*256 + threadIdx.x;          // float4 index
  float4 v = ((const float4*)s)[i];
  bf16x4 o;
  o[0]=(bf16)v.x; o[1]=(bf16)v.y; o[2]=(bf16)v.z; o[3]=(bf16)v.w;
  ((bf16x4*)d)[i] = o;
}

// ---------------- shared GEMM core (8-wave): C(128x128) = A * B^T ---------
// 512 threads = 8 waves (4 row x 2 col), wave does 32x64 out (2x4 frags).
// BK=64: 2 LDS buffers x (A 16KB + B 16KB) = 64KB -> 2 blocks/CU,
// 16 waves/CU = 4 waves/SIMD. Per K-tile: barrier; issue 4 gload16 for
// kt+1; vmcnt(4) counted; barrier; 12 ds_read_b128; 16 MFMA/wave.
// 8-chunk rotation layout -> 0 conflicts (r4-verified structure).
__device__ __forceinline__ void gemm_core8(const bf16* __restrict__ A,
                                           const bf16* __restrict__ Bw,
                                           const int row0, const int col0,
                                           bf16* __restrict__ sA, bf16* __restrict__ sB,
                                           f32x4 (&acc)[2][4])
{
  const int t = threadIdx.x;                 // 0..511
  #pragma unroll
  for (int m=0;m<2;m++)
    #pragma unroll
    for (int n=0;n<4;n++)
      acc[m][n] = (f32x4){0.f,0.f,0.f,0.f};

  const int srow = t >> 3;
  const int lch  = ((t & 7) - (srow & 7)) & 7;
  const bf16* gA = A  + (size_t)(row0 + srow)*DD + lch*8;
  const bf16* gB = Bw + (size_t)(col0 + srow)*DD + lch*8;
  char* lA = (char*)sA + t*16;               // 8KB per issue-half
  char* lB = (char*)sB + t*16;

  const int lane = t & 63, wid = t >> 6;
  const int wr = wid >> 1, wc = wid & 1;     // 4 x 2 wave grid
  const int fr = lane & 15, fg = lane >> 4;
  const int fr7 = fr & 7;

  // prologue: stage tile 0 into buffer 0
  gload16(gA,                 lA);
  gload16(gA + (size_t)64*DD, lA + 8192);
  gload16(gB,                 lB);
  gload16(gB + (size_t)64*DD, lB + 8192);

  for (int kt = 0; kt < 16; ++kt) {
    const int buf = kt & 1;
    __builtin_amdgcn_s_barrier();        // all waves done reading buf^1
    if (kt < 15) {
      const int nb = buf ^ 1;
      const int ko = (kt + 1) * 64;
      gload16(gA + ko,                 lA + nb*16384);
      gload16(gA + (size_t)64*DD + ko, lA + nb*16384 + 8192);
      gload16(gB + ko,                 lB + nb*16384);
      gload16(gB + (size_t)64*DD + ko, lB + nb*16384 + 8192);
      asm volatile("s_waitcnt vmcnt(4)" ::: "memory");   // kt's 4 done
    } else {
      asm volatile("s_waitcnt vmcnt(0)" ::: "memory");
    }
    __builtin_amdgcn_s_barrier();        // all waves' kt DMA drained
    const char* bA = (const char*)sA + buf*16384;
    const char* bB = (const char*)sB + buf*16384;
    bf16x8 aF[2][2], bF[2][4];
    #pragma unroll
    for (int kb=0;kb<2;kb++) {
      #pragma unroll
      for (int m=0;m<2;m++)
        aF[kb][m] = *(const bf16x8*)(bA + (wr*32 + m*16 + fr)*128 + ((kb*4 + fg + fr7)&7)*16);
      #pragma unroll
      for (int n=0;n<4;n++)
        bF[kb][n] = *(const bf16x8*)(bB + (wc*64 + n*16 + fr)*128 + ((kb*4 + fg + fr7)&7)*16);
    }
    __builtin_amdgcn_s_setprio(1);
    #pragma unroll
    for (int kb=0;kb<2;kb++)
      #pragma unroll
      for (int m=0;m<2;m++)
        #pragma unroll
        for (int n=0;n<4;n++)
          acc[m][n] = __builtin_amdgcn_mfma_f32_16x16x32_bf16(aF[kb][m], bF[kb][n], acc[m][n], 0, 0, 0);
    __builtin_amdgcn_s_setprio(0);
  }
}

// ---------------- GEMM 1: q/k/v = rope(x @ W^T), z picks W ----------------
__global__ __launch_bounds__(512, 2) void k_gemm_rope(
    const bf16* __restrict__ X, const bf16* __restrict__ Wq,
    const bf16* __restrict__ Wk, const bf16* __restrict__ Wv,
    bf16* __restrict__ QKV)
{
  __shared__ bf16 sA[2*128*64];   // 32 KB
  __shared__ bf16 sB[2*128*64];   // 32 KB
  const int row0 = blockIdx.x * 128;
  const int col0 = blockIdx.y * 128;
  const int z = blockIdx.z;
  const bf16* Bw = (z==0) ? Wq : ((z==1) ? Wk : Wv);
  f32x4 acc[2][4];
  gemm_core8(X, Bw, row0, col0, sA, sB, acc);

  bf16* outp = QKV + (size_t)z * (4096u*1024u);
  const int lane = threadIdx.x & 63, wid = threadIdx.x >> 6;
  const int wr = wid >> 1, wc = wid & 1;
  const int fr = lane & 15, fg = lane >> 4;
  #pragma unroll
  for (int n=0;n<4;n++) {
    const int gc = col0 + wc*64 + n*16 + fr;
    const int i2 = gc >> 1;
    // theta = 10000^(-2*(i-1)/1024) = exp((i-1) * (-2*ln(1e4)/1024))
    const float theta = __expf(((float)i2 - 1.0f) * (-2.0f * 9.210340371976184f / 1024.0f));
    #pragma unroll
    for (int m=0;m<2;m++) {
      #pragma unroll
      for (int r=0;r<4;r++) {
        const int gr = row0 + wr*32 + m*16 + fg*4 + r;
        const float v  = acc[m][n][r];
        const float pv = __shfl_xor(v, 1);      // partner column of the pair
        const int pos = gr & (MM-1);
        float sv, cv;
        __sincosf((float)pos * theta, &sv, &cv);
        const float res = (gc & 1) ? (v*cv - pv*sv) : (v*cv + pv*sv);
        outp[(size_t)gr * DD + gc] = (bf16)res;
      }
    }
  }
}

// ------- GEMM 2: qh/kh = q/k @ Wi^T + b (bf16), vh stored TRANSPOSED ------
// QH pre-scaled by 0.125*log2(e): attention scores land in log2 units.
__global__ __launch_bounds__(512, 2) void k_gemm_proj(
    const bf16* __restrict__ QKV, const bf16* __restrict__ IPW,
    const float* __restrict__ IPB,
    bf16* __restrict__ QH, bf16* __restrict__ KH, bf16* __restrict__ VT)
{
  __shared__ bf16 sA[2*128*64];
  __shared__ bf16 sB[2*128*64];
  const int row0 = blockIdx.x * 128;
  const int col0 = blockIdx.y * 128;
  const int z = blockIdx.z;
  const bf16* A  = QKV + (size_t)z * (4096u*1024u);
  const bf16* Bw = IPW + (size_t)z * (1024u*1024u);
  const float* bias = IPB + z * DD;
  f32x4 acc[2][4];
  gemm_core8(A, Bw, row0, col0, sA, sB, acc);

  const int lane = threadIdx.x & 63, wid = threadIdx.x >> 6;
  const int wr = wid >> 1, wc = wid & 1;
  const int fr = lane & 15, fg = lane >> 4;
  if (z < 2) {
    bf16* outp = (z==0) ? QH : KH;
    const float vscale = (z==0) ? 0.18033688011112042f : 1.0f;  // 0.125*log2e
    #pragma unroll
    for (int n=0;n<4;n++) {
      const int gc = col0 + wc*64 + n*16 + fr;
      const float bs = bias[gc];
      #pragma unroll
      for (int m=0;m<2;m++) {
        #pragma unroll
        for (int r=0;r<4;r++) {
          const int gr = row0 + wr*32 + m*16 + fg*4 + r;
          outp[(size_t)gr * DD + gc] = (bf16)((acc[m][n][r] + bs) * vscale);
        }
      }
    }
  } else {
    // VT layout: (B, D, M) so attention PV B-frags read contiguous along m
    #pragma unroll
    for (int n=0;n<4;n++) {
      const int gc = col0 + wc*64 + n*16 + fr;
      const float bs = bias[gc];
      #pragma unroll
      for (int m=0;m<2;m++) {
        const int gr0 = row0 + wr*32 + m*16 + fg*4;   // 4 consecutive rows
        const int b  = gr0 >> 11;
        const int m0 = gr0 & (MM-1);
        bf16x4 pk;
        #pragma unroll
        for (int r=0;r<4;r++) pk[r] = (bf16)(acc[m][n][r] + bs);
        *(bf16x4*)(VT + ((size_t)b*DD + gc)*MM + m0) = pk;
      }
    }
  }
}

// ---------------- flash attention (causal), KVBLK=64 ----------------------
// [r11/r15 measured-best config: attn ~48us, total 128.7us] 1024 blocks,
// LPT order, XCD-grouped (4 (h,b) combos per XCD -> KV L2-resident, FETCH
// 12MB). 40KB LDS -> 4 blocks/CU. 2-buffer K/V: stage kt+1 right after the
// barrier, drain vmcnt(0) one full compute-phase later (L2 ~200cy <<
// compute: hidden). Swapped QK^T: softmax lane-local, log2 domain (Q
// pre-scaled 0.125*log2e), FIXED max (P = 2^(s-32); scores bounded << 32 so
// no overflow; softmax is scale-invariant in relative precision) - no max
// tree, no rescale. P via wave-private swizzled LDS (r13: bpermute
// transpose costs MORE LDS-pipe; r16: PV-lag costs an extra barrier).
// Row-sum l via MFMA ones-operand on the idle matrix pipe; C-layout drops
// l[q] into the o_acc lanes -> zero-shuffle epilogue.
// Structure-change scorecard vs this config: 7 attempts, 7 losses.
__global__ __launch_bounds__(256) void k_attn(
    const bf16* __restrict__ QH, const bf16* __restrict__ KH,
    const bf16* __restrict__ VT, bf16* __restrict__ O)
{
  __shared__ bf16 sK[2*64*64];    // [buf][kv][d] rows of 128B, swizzled
  __shared__ bf16 sV[2*64*64];    // [buf][d][kv] (from VT), swizzled
  __shared__ bf16 sP[4*16*64];    // per-wave P tile [16 q][64 kv] swizzled
  const int idx = blockIdx.x;
  const int xcd = idx & 7;
  const int rr  = idx >> 3;                  // 0..127
  const int combo = xcd*4 + (rr & 3);        // 0..31 (4 combos per XCD)
  const int b = combo >> 4, h = combo & 15;
  const int qt = 31 - (rr >> 2);             // LPT: longest q-tiles first
  const int t = threadIdx.x, lane = t & 63, wid = t >> 6;
  const int fr = lane & 15, fg = lane >> 4;
  const int swzP = (fr & 7) << 4;
  const int q0 = qt * 64;
  const int qg = q0 + wid*16 + fr;           // this lane's q row

  // staging geometry (pre-swizzled global source, linear LDS dest t*16)
  const int srow = t >> 3;                       // 0..31
  const int cc   = (t & 7) ^ (srow & 7);
  const bf16* gK0 = KH + ((size_t)b*MM + srow)*DD + h*HD + cc*8;
  const bf16* gK1 = gK0 + (size_t)32*DD;
  const bf16* gV0 = VT + ((size_t)b*DD + h*HD + srow)*MM + cc*8;
  const bf16* gV1 = gV0 + (size_t)32*MM;
  char* lK = (char*)sK + t*16;
  char* lV = (char*)sV + t*16;
  char* sPw = (char*)(sP + wid*16*64);

  const bf16* qp = QH + ((size_t)b*MM + qg)*DD + h*HD + fg*8;
  bf16x8 aQ0 = *(const bf16x8*)qp;
  bf16x8 aQ1 = *(const bf16x8*)(qp + 32);

  bf16x8 ones;
  #pragma unroll
  for (int j=0;j<8;j++) ones[j] = (bf16)1.0f;

  // stage tile 0 into buffer 0
  gload16(gK0, lK);  gload16(gK1, lK + 4096);
  gload16(gV0, lV);  gload16(gV1, lV + 4096);

  f32x4 o_acc[4];
  #pragma unroll
  for (int n=0;n<4;n++) o_acc[n] = (f32x4){0.f,0.f,0.f,0.f};
  f32x4 lacc = (f32x4){0.f,0.f,0.f,0.f};     // softmax denominator via MFMA
  const f32x4 minit = (f32x4){-32.f,-32.f,-32.f,-32.f};

  for (int kt = 0; kt <= qt; ++kt) {
    const int buf = kt & 1;
    asm volatile("s_waitcnt vmcnt(0)" ::: "memory");  // own tile-kt DMA done
    __builtin_amdgcn_s_barrier();          // all waves' DMA done; buf^1 free
    if (kt < qt) {                         // stage next tile into buf^1
      const int nb = buf ^ 1;
      gload16(gK0 + (size_t)(kt+1)*64*DD, lK + nb*8192);
      gload16(gK1 + (size_t)(kt+1)*64*DD, lK + nb*8192 + 4096);
      gload16(gV0 + (kt+1)*64,            lV + nb*8192);
      gload16(gV1 + (kt+1)*64,            lV + nb*8192 + 4096);
    }
    const char* bKb = (const char*)sK + buf*8192;
    const char* bVb = (const char*)sV + buf*8192;

    // S^T - 32 = K Q^T + (-32) : lane holds S[kv=n*16+fg*4+r][q=fr] - 32
    f32x4 sacc[4];
    #pragma unroll
    for (int n=0;n<4;n++) sacc[n] = minit;
    __builtin_amdgcn_s_setprio(1);
    #pragma unroll
    for (int kb=0;kb<2;kb++) {
      const bf16x8 q = kb ? aQ1 : aQ0;
      #pragma unroll
      for (int n=0;n<4;n++) {
        const int rowA = n*16 + fr;
        bf16x8 aK = *(const bf16x8*)(bKb + rowA*128 + ((kb*64 + fg*16) ^ ((rowA&7)<<4)));
        sacc[n] = __builtin_amdgcn_mfma_f32_16x16x32_bf16(aK, q, sacc[n], 0, 0, 0);
      }
    }
    __builtin_amdgcn_s_setprio(0);

    // P = 2^(s - 32), masked entries -> 0  (no running max, no subtract)
    const bool diag = (kt == qt);
    float ps[16];
    #pragma unroll
    for (int n=0;n<4;n++)
      #pragma unroll
      for (int r=0;r<4;r++) {
        float xx = sacc[n][r];
        if (diag) {
          const int kvg = kt*64 + n*16 + fg*4 + r;
          if (kvg > qg) xx = -INFINITY;
        }
        ps[n*4+r] = exp2f(xx);
      }
    #pragma unroll
    for (int n=0;n<4;n++) {
      bf16x4 pk;
      #pragma unroll
      for (int r=0;r<4;r++) pk[r] = (bf16)ps[n*4+r];
      *(bf16x4*)(sPw + fr*128 + ((n*32 + fg*8) ^ swzP)) = pk;
    }
    asm volatile("s_waitcnt lgkmcnt(0)" ::: "memory");  // P visible wave-wide

    // O += P V ; l += P @ ones  (row-sum on the idle MFMA pipe)
    bf16x8 aP0 = *(const bf16x8*)(sPw + fr*128 + ((fg*16) ^ swzP));
    bf16x8 aP1 = *(const bf16x8*)(sPw + fr*128 + ((64 + fg*16) ^ swzP));
    __builtin_amdgcn_s_setprio(1);
    #pragma unroll
    for (int n=0;n<4;n++) {
      const int rowV = n*16 + fr;
      bf16x8 bV0 = *(const bf16x8*)(bVb + rowV*128 + ((fg*16) ^ ((rowV&7)<<4)));
      bf16x8 bV1 = *(const bf16x8*)(bVb + rowV*128 + ((64 + fg*16) ^ ((rowV&7)<<4)));
      o_acc[n] = __builtin_amdgcn_mfma_f32_16x16x32_bf16(aP0, bV0, o_acc[n], 0, 0, 0);
      o_acc[n] = __builtin_amdgcn_mfma_f32_16x16x32_bf16(aP1, bV1, o_acc[n], 0, 0, 0);
    }
    lacc = __builtin_amdgcn_mfma_f32_16x16x32_bf16(aP0, ones, lacc, 0, 0, 0);
    lacc = __builtin_amdgcn_mfma_f32_16x16x32_bf16(aP1, ones, lacc, 0, 0, 0);
    __builtin_amdgcn_s_setprio(0);
  }

  // epilogue: l[q=fg*4+r] sits in lacc[r] of every lane -> no shuffles
  #pragma unroll
  for (int r=0;r<4;r++) {
    const int qq = q0 + wid*16 + fg*4 + r;
    const float inv = 1.0f / lacc[r];
    #pragma unroll
    for (int n=0;n<4;n++) {
      O[((size_t)b*MM + qq)*DD + h*HD + n*16 + fr] = (bf16)(o_acc[n][r] * inv);
    }
  }
}

// ---------------- GEMM 3: out = O @ out_w^T + out_b (fp32 out) ------------
__global__ __launch_bounds__(512, 2) void k_gemm_out(
    const bf16* __restrict__ A, const bf16* __restrict__ OW,
    const float* __restrict__ OBIAS, float* __restrict__ outp)
{
  __shared__ bf16 sA[2*128*64];
  __shared__ bf16 sB[2*128*64];
  const int row0 = blockIdx.x * 128;
  const int col0 = blockIdx.y * 128;
  f32x4 acc[2][4];
  gemm_core8(A, OW, row0, col0, sA, sB, acc);
  const int lane = threadIdx.x & 63, wid = threadIdx.x >> 6;
  const int wr = wid >> 1, wc = wid & 1;
  const int fr = lane & 15, fg = lane >> 4;
  #pragma unroll
  for (int n=0;n<4;n++) {
    const int gc = col0 + wc*64 + n*16 + fr;
    const float bs = OBIAS[gc];
    #pragma unroll
    for (int m=0;m<2;m++) {
      #pragma unroll
      for (int r=0;r<4;r++) {
        const int gr = row0 + wr*32 + m*16 + fg*4 + r;
        outp[(size_t)gr * DD + gc] = acc[m][n][r] + bs;
      }
    }
  }
}

// ---------------- host launcher -------------------------------------------
extern "C" void kernel_launch(void* const* d_in, const int* in_sizes, int n_in,
                              void* d_out, int out_size, void* d_ws, size_t ws_size,
                              hipStream_t stream)
{
  (void)in_sizes; (void)n_in; (void)out_size; (void)ws_size;
  const float* x   = (const float*)d_in[0];
  const float* wq  = (const float*)d_in[1];
  const float* wk  = (const float*)d_in[2];
  const float* wv  = (const float*)d_in[3];
  const float* ipw = (const float*)d_in[4];
  const float* ipb = (const float*)d_in[5];
  const float* ow  = (const float*)d_in[6];
  const float* ob  = (const float*)d_in[7];
  float* outp = (float*)d_out;

  char* ws = (char*)d_ws;
  const size_t MB = 1u << 20;
  bf16* xb   = (bf16*)(ws + 0*MB);    // 8 MB  (4096x1024)
  bf16* wqb  = (bf16*)(ws + 8*MB);    // 2 MB
  bf16* wkb  = (bf16*)(ws + 10*MB);   // 2 MB
  bf16* wvb  = (bf16*)(ws + 12*MB);   // 2 MB
  bf16* ipwb = (bf16*)(ws + 14*MB);   // 6 MB  (3072x1024)
  bf16* owb  = (bf16*)(ws + 20*MB);   // 2 MB
  bf16* QKV  = (bf16*)(ws + 22*MB);   // 24 MB (3 x 4096x1024)
  bf16* QH   = (bf16*)(ws + 46*MB);   // 8 MB  (pre-scaled by 0.125*log2e)
  bf16* KH   = (bf16*)(ws + 54*MB);   // 8 MB
  bf16* VT   = (bf16*)(ws + 62*MB);   // 8 MB  (2 x 1024 x 2048, transposed)
  bf16* Ob   = (bf16*)(ws + 70*MB);   // 8 MB

  k_cvt_all<<<11264, 256, 0, stream>>>(x, wq, wk, wv, ipw, ow,
                                       xb, wqb, wkb, wvb, ipwb, owb);
  k_gemm_rope<<<dim3(32,8,3), 512, 0, stream>>>(xb, wqb, wkb, wvb, QKV);
  k_gemm_proj<<<dim3(32,8,3), 512, 0, stream>>>(QKV, ipwb, ipb, QH, KH, VT);
  k_attn<<<1024, 256, 0, stream>>>(QH, KH, VT, Ob);
  k_gemm_out<<<dim3(32,8,1), 512, 0, stream>>>(Ob, owb, ob, outp);
}